// Round 1
// baseline (1004.560 us; speedup 1.0000x reference)
//
#include <hip/hip_runtime.h>
#include <cstdint>
#include <cstddef>

// ---------------- degree / norm ----------------

__global__ void deg_init(float* __restrict__ deg, int N) {
    int i = blockIdx.x * blockDim.x + threadIdx.x;
    if (i < N) deg[i] = 1.0f;  // self-loop
}

__global__ void deg_count(const int* __restrict__ dst, float* __restrict__ deg, int E) {
    int e = blockIdx.x * blockDim.x + threadIdx.x;
    if (e < E) unsafeAtomicAdd(&deg[dst[e]], 1.0f);
}

__global__ void deg_rsqrt(float* __restrict__ deg, int N) {
    int i = blockIdx.x * blockDim.x + threadIdx.x;
    if (i < N) deg[i] = rsqrtf(deg[i]);
}

// ---------------- GEMM: Y[N x 64] = X[N x K] @ W[K x 64] ----------------
// Block = 256 threads, 64 rows per block, 4x4 register tile per thread.
// LDS: xs padded by +4 floats/row (2-way bank aliasing only -> free).

template <int K>
__global__ __launch_bounds__(256) void gemm64(const float* __restrict__ X,
                                              const float* __restrict__ W,
                                              float* __restrict__ Y, int N) {
    constexpr int LDX = K + 4;
    __shared__ float xs[64 * LDX];
    __shared__ float ws[K * 64];

    const int tid  = threadIdx.x;
    const int row0 = blockIdx.x * 64;

    // stage W (K*64 floats, contiguous)
    const float4* W4 = (const float4*)W;
    for (int i = tid; i < K * 16; i += 256) ((float4*)ws)[i] = W4[i];

    // stage 64 rows of X (contiguous 64*K floats), zero-pad past N
    const float4* X4  = (const float4*)(X + (size_t)row0 * K);
    const int     nf4 = (row0 < N ? min(64, N - row0) : 0) * (K / 4);
    for (int i = tid; i < 16 * K; i += 256) {
        float4 v = make_float4(0.f, 0.f, 0.f, 0.f);
        if (i < nf4) v = X4[i];
        int r  = i / (K / 4);
        int kk = (i % (K / 4)) * 4;
        *(float4*)&xs[r * LDX + kk] = v;
    }
    __syncthreads();

    const int cg = tid & 15;   // col group: cols cg*4 .. cg*4+3
    const int rg = tid >> 4;   // row group: rows rg*4 .. rg*4+3

    float acc[4][4] = {};
    for (int k = 0; k < K; k += 4) {
        float4 xf[4], wf[4];
#pragma unroll
        for (int i = 0; i < 4; i++) xf[i] = *(const float4*)&xs[(rg * 4 + i) * LDX + k];
#pragma unroll
        for (int j = 0; j < 4; j++) wf[j] = *(const float4*)&ws[(k + j) * 64 + cg * 4];
#pragma unroll
        for (int i = 0; i < 4; i++) {
            float4 xv = xf[i];
            acc[i][0] += xv.x * wf[0].x + xv.y * wf[1].x + xv.z * wf[2].x + xv.w * wf[3].x;
            acc[i][1] += xv.x * wf[0].y + xv.y * wf[1].y + xv.z * wf[2].y + xv.w * wf[3].y;
            acc[i][2] += xv.x * wf[0].z + xv.y * wf[1].z + xv.z * wf[2].z + xv.w * wf[3].z;
            acc[i][3] += xv.x * wf[0].w + xv.y * wf[1].w + xv.z * wf[2].w + xv.w * wf[3].w;
        }
    }

#pragma unroll
    for (int i = 0; i < 4; i++) {
        int r = row0 + rg * 4 + i;
        if (r < N)
            *(float4*)&Y[(size_t)r * 64 + cg * 4] =
                make_float4(acc[i][0], acc[i][1], acc[i][2], acc[i][3]);
    }
}

// ---------------- edge scatter: agg[dst] += B[src] * dis[src]*dis[dst] ----------------
// One wave = 64 edges staged in registers; lane = channel. Gather is one
// coalesced 256B load per edge; 64 f32 atomics per edge.

__global__ __launch_bounds__(256) void scatter64(const float* __restrict__ B,
                                                 const int* __restrict__ src,
                                                 const int* __restrict__ dst,
                                                 const float* __restrict__ dis,
                                                 float* __restrict__ agg, int E) {
    const int lane = threadIdx.x & 63;
    const int gw   = (int)((blockIdx.x * blockDim.x + threadIdx.x) >> 6);
    const int base = gw * 64;
    if (base >= E) return;

    int   s = 0, d = 0;
    float nrm = 0.0f;
    int   e = base + lane;
    if (e < E) {
        s   = src[e];
        d   = dst[e];
        nrm = dis[s] * dis[d];
    }
    const int cnt = min(64, E - base);
    for (int j = 0; j < cnt; j++) {
        int   sj = __shfl(s, j);
        int   dj = __shfl(d, j);
        float nj = __shfl(nrm, j);
        float v  = B[sj * 64 + lane] * nj;
        unsafeAtomicAdd(&agg[dj * 64 + lane], v);
    }
}

// ---------------- epilogue 1: h = relu(agg + xw*dis^2 + b1), in place over xw ----------------

__global__ void epi1(float* __restrict__ XW, const float* __restrict__ AGG,
                     const float* __restrict__ dis, const float* __restrict__ b1, int N) {
    int idx = blockIdx.x * blockDim.x + threadIdx.x;  // over N*16 float4s
    if (idx >= N * 16) return;
    int    row = idx >> 4;
    int    c4  = (idx & 15) * 4;
    float  di  = dis[row];
    float  n   = di * di;
    float4 xw  = ((const float4*)XW)[idx];
    float4 ag  = ((const float4*)AGG)[idx];
    float4 bb  = *(const float4*)&b1[c4];
    float4 o;
    o.x = fmaxf(ag.x + xw.x * n + bb.x, 0.f);
    o.y = fmaxf(ag.y + xw.y * n + bb.y, 0.f);
    o.z = fmaxf(ag.z + xw.z * n + bb.z, 0.f);
    o.w = fmaxf(ag.w + xw.w * n + bb.w, 0.f);
    ((float4*)XW)[idx] = o;
}

// ---------------- epilogue 2: out = log_softmax(agg + hw*dis^2 + b2), wave per row ----------------

__global__ __launch_bounds__(256) void epi2_lsm(float* __restrict__ OUT,
                                                const float* __restrict__ HW,
                                                const float* __restrict__ dis,
                                                const float* __restrict__ b2, int N) {
    int row  = (int)((blockIdx.x * blockDim.x + threadIdx.x) >> 6);
    int lane = threadIdx.x & 63;
    if (row >= N) return;
    float di  = dis[row];
    int   idx = row * 64 + lane;
    float v   = OUT[idx] + HW[idx] * di * di + b2[lane];

    float m = v;
#pragma unroll
    for (int off = 32; off; off >>= 1) m = fmaxf(m, __shfl_xor(m, off));
    float s = __expf(v - m);
#pragma unroll
    for (int off = 32; off; off >>= 1) s += __shfl_xor(s, off);
    OUT[idx] = v - m - __logf(s);
}

// ---------------- launch ----------------

extern "C" void kernel_launch(void* const* d_in, const int* in_sizes, int n_in,
                              void* d_out, int out_size, void* d_ws, size_t ws_size,
                              hipStream_t stream) {
    const float* x  = (const float*)d_in[0];
    const int*   ei = (const int*)d_in[1];
    const float* W1 = (const float*)d_in[2];
    const float* b1 = (const float*)d_in[3];
    const float* W2 = (const float*)d_in[4];
    const float* b2 = (const float*)d_in[5];
    float*       out = (float*)d_out;

    const int N = in_sizes[0] / 128;
    const int E = in_sizes[1] / 2;
    const int* src = ei;
    const int* dst = ei + E;

    float* dis = (float*)d_ws;
    float* B0  = dis + (((size_t)N + 255) & ~(size_t)255);  // xw1, then h (in place)
    float* B1  = B0 + (size_t)N * 64;                       // agg1, then hw2

    hipMemsetAsync(B1, 0, (size_t)N * 64 * sizeof(float), stream);   // agg1 = 0
    hipMemsetAsync(out, 0, (size_t)N * 64 * sizeof(float), stream);  // agg2 = 0

    deg_init<<<(N + 255) / 256, 256, 0, stream>>>(dis, N);
    deg_count<<<(E + 255) / 256, 256, 0, stream>>>(dst, dis, E);
    deg_rsqrt<<<(N + 255) / 256, 256, 0, stream>>>(dis, N);

    gemm64<128><<<(N + 63) / 64, 256, 0, stream>>>(x, W1, B0, N);
    scatter64<<<(E + 255) / 256, 256, 0, stream>>>(B0, src, dst, dis, B1, E);
    epi1<<<(N * 16 + 255) / 256, 256, 0, stream>>>(B0, B1, dis, b1, N);

    gemm64<64><<<(N + 63) / 64, 256, 0, stream>>>(B0, W2, B1, N);
    scatter64<<<(E + 255) / 256, 256, 0, stream>>>(B1, src, dst, dis, out, E);
    epi2_lsm<<<(N * 64 + 255) / 256, 256, 0, stream>>>(out, B1, dis, b2, N);
}

// Round 2
// 752.078 us; speedup vs baseline: 1.3357x; 1.3357x over previous
//
#include <hip/hip_runtime.h>
#include <cstdint>
#include <cstddef>

// ---------------- histogram / dis ----------------

__global__ void hist_count(const int* __restrict__ dst, int* __restrict__ hist, int E) {
    int e = blockIdx.x * blockDim.x + threadIdx.x;
    if (e < E) atomicAdd(&hist[dst[e]], 1);
}

__global__ void dis_k(const int* __restrict__ hist, float* __restrict__ dis, int N) {
    int i = blockIdx.x * blockDim.x + threadIdx.x;
    if (i < N) dis[i] = rsqrtf((float)(hist[i] + 1));  // +1 = self loop
}

// single-block exclusive scan: hist[0..N) -> ptr[0..N]
__global__ __launch_bounds__(1024) void scan_k(const int* __restrict__ hist,
                                               int* __restrict__ ptr, int N) {
    __shared__ int lsum[1024];
    const int t     = threadIdx.x;
    const int chunk = (N + 1023) / 1024;
    const int lo    = t * chunk;
    const int hi    = min(lo + chunk, N);
    int s = 0;
    for (int i = lo; i < hi; i++) s += hist[i];
    lsum[t] = s;
    __syncthreads();
    for (int off = 1; off < 1024; off <<= 1) {
        int v = (t >= off) ? lsum[t - off] : 0;
        __syncthreads();
        lsum[t] += v;
        __syncthreads();
    }
    int run = (t > 0) ? lsum[t - 1] : 0;
    for (int i = lo; i < hi; i++) {
        ptr[i] = run;
        run += hist[i];
    }
    if (t == 1023) ptr[N] = lsum[1023];
}

__global__ void copy_k(const int* __restrict__ a, int* __restrict__ b, int N) {
    int i = blockIdx.x * blockDim.x + threadIdx.x;
    if (i < N) b[i] = a[i];
}

__global__ void fill_k(const int* __restrict__ src, const int* __restrict__ dst,
                       int* __restrict__ cursor, int* __restrict__ csr, int E) {
    int e = blockIdx.x * blockDim.x + threadIdx.x;
    if (e < E) {
        int pos  = atomicAdd(&cursor[dst[e]], 1);
        csr[pos] = src[e];
    }
}

// ---------------- GEMM: Y[N x 64] = X[N x K] @ W[K x 64] ----------------
// In-place safe (Y may alias X): block stages its own 64 rows to LDS first.

template <int K>
__global__ __launch_bounds__(256) void gemm64(const float* __restrict__ X,
                                              const float* __restrict__ W,
                                              float* __restrict__ Y, int N) {
    constexpr int LDX = K + 4;
    __shared__ float xs[64 * LDX];
    __shared__ float ws[K * 64];

    const int tid  = threadIdx.x;
    const int row0 = blockIdx.x * 64;

    const float4* W4 = (const float4*)W;
    for (int i = tid; i < K * 16; i += 256) ((float4*)ws)[i] = W4[i];

    const float4* X4  = (const float4*)(X + (size_t)row0 * K);
    const int     nf4 = (row0 < N ? min(64, N - row0) : 0) * (K / 4);
    for (int i = tid; i < 16 * K; i += 256) {
        float4 v = make_float4(0.f, 0.f, 0.f, 0.f);
        if (i < nf4) v = X4[i];
        int r  = i / (K / 4);
        int kk = (i % (K / 4)) * 4;
        *(float4*)&xs[r * LDX + kk] = v;
    }
    __syncthreads();

    const int cg = tid & 15;
    const int rg = tid >> 4;

    float acc[4][4] = {};
    for (int k = 0; k < K; k += 4) {
        float4 xf[4], wf[4];
#pragma unroll
        for (int i = 0; i < 4; i++) xf[i] = *(const float4*)&xs[(rg * 4 + i) * LDX + k];
#pragma unroll
        for (int j = 0; j < 4; j++) wf[j] = *(const float4*)&ws[(k + j) * 64 + cg * 4];
#pragma unroll
        for (int i = 0; i < 4; i++) {
            float4 xv = xf[i];
            acc[i][0] += xv.x * wf[0].x + xv.y * wf[1].x + xv.z * wf[2].x + xv.w * wf[3].x;
            acc[i][1] += xv.x * wf[0].y + xv.y * wf[1].y + xv.z * wf[2].y + xv.w * wf[3].y;
            acc[i][2] += xv.x * wf[0].z + xv.y * wf[1].z + xv.z * wf[2].z + xv.w * wf[3].z;
            acc[i][3] += xv.x * wf[0].w + xv.y * wf[1].w + xv.z * wf[2].w + xv.w * wf[3].w;
        }
    }
    __syncthreads();  // in-place: ensure all reads of X done before Y writes when aliased

#pragma unroll
    for (int i = 0; i < 4; i++) {
        int r = row0 + rg * 4 + i;
        if (r < N)
            *(float4*)&Y[(size_t)r * 64 + cg * 4] =
                make_float4(acc[i][0], acc[i][1], acc[i][2], acc[i][3]);
    }
}

// ---------------- pull aggregation, fused epilogue ----------------
// One wave per dst row; lane = channel. acc = B[row]*dis[row] + sum_e B[src_e]*dis[src_e]
// result = acc*dis[row] + bias ; MODE 0: relu ; MODE 1: log_softmax over 64 lanes.

template <int MODE>
__global__ __launch_bounds__(256) void agg64(const float* __restrict__ B,
                                             const int* __restrict__ csr,
                                             const int* __restrict__ ptr,
                                             const float* __restrict__ dis,
                                             const float* __restrict__ bias,
                                             float* __restrict__ out, int N) {
    const int row  = blockIdx.x * 4 + (threadIdx.x >> 6);
    const int lane = threadIdx.x & 63;
    if (row >= N) return;

    const int   s0 = ptr[row];
    const int   s1 = ptr[row + 1];
    const float di = dis[row];

    float acc = B[(size_t)row * 64 + lane] * di;  // self-loop term

    for (int base = s0; base < s1; base += 64) {
        int   sv = 0;
        float wv = 0.0f;
        int   e  = base + lane;
        if (e < s1) {
            sv = csr[e];
            wv = dis[sv];
        }
        const int cnt = min(64, s1 - base);
        for (int j = 0; j < cnt; j++) {
            int   s = __shfl(sv, j);
            float w = __shfl(wv, j);
            acc += B[(size_t)s * 64 + lane] * w;
        }
    }

    float v = acc * di + bias[lane];

    if (MODE == 0) {
        out[(size_t)row * 64 + lane] = fmaxf(v, 0.0f);
    } else {
        float m = v;
#pragma unroll
        for (int off = 32; off; off >>= 1) m = fmaxf(m, __shfl_xor(m, off));
        float s = __expf(v - m);
#pragma unroll
        for (int off = 32; off; off >>= 1) s += __shfl_xor(s, off);
        out[(size_t)row * 64 + lane] = v - m - __logf(s);
    }
}

// ---------------- launch ----------------

extern "C" void kernel_launch(void* const* d_in, const int* in_sizes, int n_in,
                              void* d_out, int out_size, void* d_ws, size_t ws_size,
                              hipStream_t stream) {
    const float* x   = (const float*)d_in[0];
    const int*   ei  = (const int*)d_in[1];
    const float* W1  = (const float*)d_in[2];
    const float* b1  = (const float*)d_in[3];
    const float* W2  = (const float*)d_in[4];
    const float* b2  = (const float*)d_in[5];
    float*       out = (float*)d_out;

    const int  N   = in_sizes[0] / 128;
    const int  E   = in_sizes[1] / 2;
    const int* src = ei;
    const int* dst = ei + E;

    auto align256 = [](size_t v) { return (v + 255) & ~(size_t)255; };
    char*  p      = (char*)d_ws;
    float* dis    = (float*)p;           p += align256((size_t)N * 4);
    int*   ptr    = (int*)p;             p += align256((size_t)(N + 1) * 4);
    int*   hist   = (int*)p;             p += align256((size_t)N * 4);
    int*   cursor = (int*)p;             p += align256((size_t)N * 4);
    int*   csr    = (int*)p;             p += align256((size_t)E * 4);
    float* H      = (float*)p;           p += align256((size_t)N * 64 * 4);
    float* xw     = out;                 // d_out doubles as scratch for layer-1 xw

    hipMemsetAsync(hist, 0, (size_t)N * sizeof(int), stream);
    hist_count<<<(E + 255) / 256, 256, 0, stream>>>(dst, hist, E);
    dis_k<<<(N + 255) / 256, 256, 0, stream>>>(hist, dis, N);
    scan_k<<<1, 1024, 0, stream>>>(hist, ptr, N);
    copy_k<<<(N + 255) / 256, 256, 0, stream>>>(ptr, cursor, N);
    fill_k<<<(E + 255) / 256, 256, 0, stream>>>(src, dst, cursor, csr, E);

    gemm64<128><<<(N + 63) / 64, 256, 0, stream>>>(x, W1, xw, N);
    agg64<0><<<(N + 3) / 4, 256, 0, stream>>>(xw, csr, ptr, dis, b1, H, N);

    gemm64<64><<<(N + 63) / 64, 256, 0, stream>>>(H, W2, H, N);  // in-place
    agg64<1><<<(N + 3) / 4, 256, 0, stream>>>(H, csr, ptr, dis, b2, out, N);
}

// Round 3
// 516.911 us; speedup vs baseline: 1.9434x; 1.4549x over previous
//
#include <hip/hip_runtime.h>
#include <cstdint>
#include <cstddef>

// ---------------- histogram / dis ----------------

__global__ void hist_count(const int* __restrict__ dst, int* __restrict__ hist, int E) {
    int e = blockIdx.x * blockDim.x + threadIdx.x;
    if (e < E) atomicAdd(&hist[dst[e]], 1);
}

__global__ void dis_k(const int* __restrict__ hist, float* __restrict__ dis, int N) {
    int i = blockIdx.x * blockDim.x + threadIdx.x;
    if (i < N) dis[i] = rsqrtf((float)(hist[i] + 1));  // +1 = self loop
}

// ---------------- 3-phase exclusive scan over hist[0..N) -> ptr[0..N], cursor ----
// 1024 elements per block (4 per thread).

__global__ __launch_bounds__(256) void scan_partial(const int* __restrict__ hist,
                                                    int* __restrict__ partials, int N) {
    __shared__ int red[256];
    const int t    = threadIdx.x;
    const int base = blockIdx.x * 1024 + t * 4;
    int s = 0;
    if (base + 3 < N) {
        int4 v = *(const int4*)&hist[base];
        s = v.x + v.y + v.z + v.w;
    } else {
        for (int i = 0; i < 4; i++)
            if (base + i < N) s += hist[base + i];
    }
    red[t] = s;
    __syncthreads();
    for (int off = 128; off; off >>= 1) {
        if (t < off) red[t] += red[t + off];
        __syncthreads();
    }
    if (t == 0) partials[blockIdx.x] = red[0];
}

// single block, NB <= 256 partials -> exclusive offsets in place
__global__ __launch_bounds__(256) void scan_offsets(int* __restrict__ partials, int NB) {
    __shared__ int tmp[256];
    const int t = threadIdx.x;
    int v = (t < NB) ? partials[t] : 0;
    tmp[t] = v;
    __syncthreads();
    for (int off = 1; off < 256; off <<= 1) {
        int u = (t >= off) ? tmp[t - off] : 0;
        __syncthreads();
        tmp[t] += u;
        __syncthreads();
    }
    if (t < NB) partials[t] = tmp[t] - v;
}

__global__ __launch_bounds__(256) void scan_apply(const int* __restrict__ hist,
                                                  const int* __restrict__ partials,
                                                  int* __restrict__ ptr,
                                                  int* __restrict__ cursor, int N) {
    __shared__ int tsum[256];
    const int t    = threadIdx.x;
    const int base = blockIdx.x * 1024 + t * 4;
    int v[4];
    int s = 0;
    for (int i = 0; i < 4; i++) {
        v[i] = (base + i < N) ? hist[base + i] : 0;
        s += v[i];
    }
    tsum[t] = s;
    __syncthreads();
    for (int off = 1; off < 256; off <<= 1) {
        int u = (t >= off) ? tsum[t - off] : 0;
        __syncthreads();
        tsum[t] += u;
        __syncthreads();
    }
    int run = partials[blockIdx.x] + tsum[t] - s;  // exclusive prefix for this thread
    for (int i = 0; i < 4; i++) {
        if (base + i < N) {
            ptr[base + i]    = run;
            cursor[base + i] = run;
            run += v[i];
        }
    }
    if (base <= N - 1 && N - 1 < base + 4) ptr[N] = run;  // total = E
}

__global__ void fill_k(const int* __restrict__ src, const int* __restrict__ dst,
                       int* __restrict__ cursor, int* __restrict__ csr, int E) {
    int e = blockIdx.x * blockDim.x + threadIdx.x;
    if (e < E) {
        int pos  = atomicAdd(&cursor[dst[e]], 1);
        csr[pos] = src[e];
    }
}

// ---------------- GEMM: Y[N x 64] = X[N x K] @ W[K x 64] ----------------
// In-place safe (Y may alias X): block stages its own 64 rows to LDS first.

template <int K>
__global__ __launch_bounds__(256) void gemm64(const float* __restrict__ X,
                                              const float* __restrict__ W,
                                              float* __restrict__ Y, int N) {
    constexpr int LDX = K + 4;
    __shared__ float xs[64 * LDX];
    __shared__ float ws[K * 64];

    const int tid  = threadIdx.x;
    const int row0 = blockIdx.x * 64;

    const float4* W4 = (const float4*)W;
    for (int i = tid; i < K * 16; i += 256) ((float4*)ws)[i] = W4[i];

    const float4* X4  = (const float4*)(X + (size_t)row0 * K);
    const int     nf4 = (row0 < N ? min(64, N - row0) : 0) * (K / 4);
    for (int i = tid; i < 16 * K; i += 256) {
        float4 v = make_float4(0.f, 0.f, 0.f, 0.f);
        if (i < nf4) v = X4[i];
        int r  = i / (K / 4);
        int kk = (i % (K / 4)) * 4;
        *(float4*)&xs[r * LDX + kk] = v;
    }
    __syncthreads();

    const int cg = tid & 15;
    const int rg = tid >> 4;

    float acc[4][4] = {};
    for (int k = 0; k < K; k += 4) {
        float4 xf[4], wf[4];
#pragma unroll
        for (int i = 0; i < 4; i++) xf[i] = *(const float4*)&xs[(rg * 4 + i) * LDX + k];
#pragma unroll
        for (int j = 0; j < 4; j++) wf[j] = *(const float4*)&ws[(k + j) * 64 + cg * 4];
#pragma unroll
        for (int i = 0; i < 4; i++) {
            float4 xv = xf[i];
            acc[i][0] += xv.x * wf[0].x + xv.y * wf[1].x + xv.z * wf[2].x + xv.w * wf[3].x;
            acc[i][1] += xv.x * wf[0].y + xv.y * wf[1].y + xv.z * wf[2].y + xv.w * wf[3].y;
            acc[i][2] += xv.x * wf[0].z + xv.y * wf[1].z + xv.z * wf[2].z + xv.w * wf[3].z;
            acc[i][3] += xv.x * wf[0].w + xv.y * wf[1].w + xv.z * wf[2].w + xv.w * wf[3].w;
        }
    }
    __syncthreads();  // in-place: all reads of X done before Y writes when aliased

#pragma unroll
    for (int i = 0; i < 4; i++) {
        int r = row0 + rg * 4 + i;
        if (r < N)
            *(float4*)&Y[(size_t)r * 64 + cg * 4] =
                make_float4(acc[i][0], acc[i][1], acc[i][2], acc[i][3]);
    }
}

// ---------------- pull aggregation, fused epilogue (float4 / 4-edges-per-iter) ----
// One wave per dst row. lane = eg*16 + cq : eg = edge subgroup (0..3),
// cq = channel quad (0..15) covering channels cq*4..cq*4+3.
// acc = sum_e B[src_e]*dis[src_e]; result = (acc + B[row]*di)*di + bias;
// MODE 0: relu ; MODE 1: log_softmax over the 64 channels.

template <int MODE>
__global__ __launch_bounds__(256) void agg64(const float* __restrict__ B,
                                             const int* __restrict__ csr,
                                             const int* __restrict__ ptr,
                                             const float* __restrict__ dis,
                                             const float* __restrict__ bias,
                                             float* __restrict__ out, int N) {
    const int row  = blockIdx.x * 4 + (threadIdx.x >> 6);
    const int lane = threadIdx.x & 63;
    if (row >= N) return;
    const int eg = lane >> 4;
    const int cq = lane & 15;

    const int   s0 = ptr[row];
    const int   s1 = ptr[row + 1];
    const float di = dis[row];

    float4 acc = make_float4(0.f, 0.f, 0.f, 0.f);

    for (int base = s0; base < s1; base += 64) {
        int   sv = 0;
        float wv = 0.0f;
        int   e  = base + lane;
        if (e < s1) {
            sv = csr[e];
            wv = dis[sv];
        }
        const int cnt = min(64, s1 - base);
        for (int g = 0; g < cnt; g += 4) {
            int    s  = __shfl(sv, g + eg);   // lanes beyond cnt carry w=0
            float  w  = __shfl(wv, g + eg);
            float4 bv = *(const float4*)&B[(size_t)s * 64 + cq * 4];
            acc.x += bv.x * w;
            acc.y += bv.y * w;
            acc.z += bv.z * w;
            acc.w += bv.w * w;
        }
    }

    // reduce across edge subgroups (lane bits 4,5)
#pragma unroll
    for (int off = 16; off <= 32; off <<= 1) {
        acc.x += __shfl_xor(acc.x, off);
        acc.y += __shfl_xor(acc.y, off);
        acc.z += __shfl_xor(acc.z, off);
        acc.w += __shfl_xor(acc.w, off);
    }

    const float4 bs = *(const float4*)&B[(size_t)row * 64 + cq * 4];
    const float4 bb = *(const float4*)&bias[cq * 4];
    float4 v;
    v.x = (acc.x + bs.x * di) * di + bb.x;
    v.y = (acc.y + bs.y * di) * di + bb.y;
    v.z = (acc.z + bs.z * di) * di + bb.z;
    v.w = (acc.w + bs.w * di) * di + bb.w;

    if (MODE == 0) {
        if (eg == 0)
            *(float4*)&out[(size_t)row * 64 + cq * 4] =
                make_float4(fmaxf(v.x, 0.f), fmaxf(v.y, 0.f), fmaxf(v.z, 0.f), fmaxf(v.w, 0.f));
    } else {
        float m = fmaxf(fmaxf(v.x, v.y), fmaxf(v.z, v.w));
#pragma unroll
        for (int off = 1; off <= 8; off <<= 1) m = fmaxf(m, __shfl_xor(m, off));
        float s = __expf(v.x - m) + __expf(v.y - m) + __expf(v.z - m) + __expf(v.w - m);
#pragma unroll
        for (int off = 1; off <= 8; off <<= 1) s += __shfl_xor(s, off);
        float lse = m + __logf(s);
        if (eg == 0)
            *(float4*)&out[(size_t)row * 64 + cq * 4] =
                make_float4(v.x - lse, v.y - lse, v.z - lse, v.w - lse);
    }
}

// ---------------- launch ----------------

extern "C" void kernel_launch(void* const* d_in, const int* in_sizes, int n_in,
                              void* d_out, int out_size, void* d_ws, size_t ws_size,
                              hipStream_t stream) {
    const float* x   = (const float*)d_in[0];
    const int*   ei  = (const int*)d_in[1];
    const float* W1  = (const float*)d_in[2];
    const float* b1  = (const float*)d_in[3];
    const float* W2  = (const float*)d_in[4];
    const float* b2  = (const float*)d_in[5];
    float*       out = (float*)d_out;

    const int  N   = in_sizes[0] / 128;
    const int  E   = in_sizes[1] / 2;
    const int* src = ei;
    const int* dst = ei + E;
    const int  NB  = (N + 1023) / 1024;

    auto align256 = [](size_t v) { return (v + 255) & ~(size_t)255; };
    char*  p        = (char*)d_ws;
    float* dis      = (float*)p;  p += align256((size_t)N * 4);
    int*   ptr      = (int*)p;    p += align256((size_t)(N + 1) * 4);
    int*   hist     = (int*)p;    p += align256((size_t)N * 4);
    int*   cursor   = (int*)p;    p += align256((size_t)N * 4);
    int*   partials = (int*)p;    p += align256((size_t)NB * 4);
    int*   csr      = (int*)p;    p += align256((size_t)E * 4);
    float* H        = (float*)p;  p += align256((size_t)N * 64 * 4);
    float* xw       = out;  // d_out doubles as scratch for layer-1 xw

    hipMemsetAsync(hist, 0, (size_t)N * sizeof(int), stream);
    hist_count<<<(E + 255) / 256, 256, 0, stream>>>(dst, hist, E);
    dis_k<<<(N + 255) / 256, 256, 0, stream>>>(hist, dis, N);
    scan_partial<<<NB, 256, 0, stream>>>(hist, partials, N);
    scan_offsets<<<1, 256, 0, stream>>>(partials, NB);
    scan_apply<<<NB, 256, 0, stream>>>(hist, partials, ptr, cursor, N);
    fill_k<<<(E + 255) / 256, 256, 0, stream>>>(src, dst, cursor, csr, E);

    gemm64<128><<<(N + 63) / 64, 256, 0, stream>>>(x, W1, xw, N);
    agg64<0><<<(N + 3) / 4, 256, 0, stream>>>(xw, csr, ptr, dis, b1, H, N);

    gemm64<64><<<(N + 63) / 64, 256, 0, stream>>>(H, W2, H, N);  // in-place
    agg64<1><<<(N + 3) / 4, 256, 0, stream>>>(H, csr, ptr, dis, b2, out, N);
}